// Round 1
// baseline (653.965 us; speedup 1.0000x reference)
//
#include <hip/hip_runtime.h>
#include <hip/hip_bf16.h>
#include <math.h>

#define NN   65536
#define EE   524288
#define BB   128
#define NPGC 512
#define HCC  192
#define KSEL 256
#define FULLE (EE + NN)   // 589824
#define NEG  0.2f

// ---------------------------------------------------------------------------
// K0: a_edge coefficients. a_edge[e,h] = ea0*A0[h] + ea1*A1[h],
//     A0[h] = sum_c W_edge[(h*64+c)*2+0]*att_edge[h*64+c], A1 likewise.
__global__ void k_acoef(const float* __restrict__ W_edge,
                        const float* __restrict__ att_edge,
                        float* __restrict__ acoef) {
    __shared__ float red[6];
    int t = threadIdx.x;            // 192 threads
    if (t < 6) red[t] = 0.f;
    __syncthreads();
    float ae = att_edge[t];
    int h = t >> 6;
    atomicAdd(&red[h],     W_edge[2*t]   * ae);
    atomicAdd(&red[3 + h], W_edge[2*t+1] * ae);
    __syncthreads();
    if (t < 6) acoef[t] = red[t];
}

// ---------------------------------------------------------------------------
// K1: per-node features. 32 nodes/block, 128 threads.
//  h = elu(x @ W_lin^T + b_lin)            [N,32]
//  xp = h @ W_src^T                        [N,192]
//  a_src[n,h] = sum_c xp[n,h,c]*att_src[h,c]; a_dst likewise
__global__ __launch_bounds__(128) void k_feat(
    const float* __restrict__ x, const float* __restrict__ W_lin,
    const float* __restrict__ b_lin, const float* __restrict__ W_src,
    const float* __restrict__ att_src, const float* __restrict__ att_dst,
    float* __restrict__ xp, float* __restrict__ a_src, float* __restrict__ a_dst) {
    __shared__ float Xs[32 * 128];
    __shared__ float WlT[128 * 33];   // [k][j] padded: bank = (k+j)%32
    __shared__ float Hs[32 * 32];
    __shared__ float WsT[32 * 193];   // [k][j] padded
    __shared__ float as_s[96], ad_s[96];
    int t = threadIdx.x;
    int base = blockIdx.x * 32;
    if (t < 96) { as_s[t] = 0.f; ad_s[t] = 0.f; }
    for (int i = 0; i < 32; ++i) {          // X tile + W_lin (both 4096 elems)
        int o = t + i * 128;
        Xs[o] = x[(size_t)base * 128 + o];
        int j = o >> 7, k = o & 127;        // W_lin row-major [32][128]
        WlT[k * 33 + j] = W_lin[o];
    }
    for (int i = 0; i < 48; ++i) {          // W_src [192][32] = 6144
        int o = t + i * 128;
        int j = o >> 5, k = o & 31;
        WsT[k * 193 + j] = W_src[o];
    }
    __syncthreads();
    for (int i = 0; i < 8; ++i) {           // h: 32 nodes x 32 outputs
        int o = t + i * 128;
        int node = o >> 5, j = o & 31;
        float s = b_lin[j];
        const float* xr = &Xs[node * 128];
        for (int k = 0; k < 128; ++k) s += xr[k] * WlT[k * 33 + j];
        s = s > 0.f ? s : expm1f(s);        // ELU(alpha=1)
        Hs[node * 32 + j] = s;
    }
    __syncthreads();
    for (int i = 0; i < 48; ++i) {          // xp: 32 nodes x 192 outputs
        int o = t + i * 128;
        int node = o / 192, j = o - node * 192;
        float s = 0.f;
        const float* hr = &Hs[node * 32];
        for (int k = 0; k < 32; ++k) s += hr[k] * WsT[k * 193 + j];
        xp[(size_t)(base + node) * HCC + j] = s;
        int h = j >> 6;
        atomicAdd(&as_s[node * 3 + h], s * att_src[j]);
        atomicAdd(&ad_s[node * 3 + h], s * att_dst[j]);
    }
    __syncthreads();
    if (t < 96) {
        a_src[base * 3 + t] = as_s[t];
        a_dst[base * 3 + t] = ad_s[t];
    }
}

// ---------------------------------------------------------------------------
// K2: in-degree + loop_attr sums (edge-parallel)
__global__ void k_deg(const int* __restrict__ ei, const float* __restrict__ ea,
                      int* __restrict__ cnt, float* __restrict__ la) {
    int e = blockIdx.x * 256 + threadIdx.x;
    int d = ei[EE + e];
    atomicAdd(&cnt[d], 1);
    atomicAdd(&la[2 * d],     ea[2 * e]);
    atomicAdd(&la[2 * d + 1], ea[2 * e + 1]);
}

// ---------------------------------------------------------------------------
// K3: exclusive scan of sizes[n]=cnt[n]+1 -> row_ptr (2-level, 256x256)
__global__ __launch_bounds__(256) void k_scan1(const int* __restrict__ cnt,
                                               int* __restrict__ rp,
                                               int* __restrict__ bsum) {
    __shared__ int tmp[256];
    int t = threadIdx.x, gid = blockIdx.x * 256 + t;
    int v = cnt[gid] + 1;
    tmp[t] = v;
    __syncthreads();
    for (int off = 1; off < 256; off <<= 1) {
        int u = (t >= off) ? tmp[t - off] : 0;
        __syncthreads();
        tmp[t] += u;
        __syncthreads();
    }
    rp[gid] = tmp[t] - v;                 // block-local exclusive
    if (t == 255) bsum[blockIdx.x] = tmp[255];
}
__global__ __launch_bounds__(256) void k_scan2(const int* __restrict__ bsum,
                                               int* __restrict__ boff) {
    __shared__ int tmp[256];
    int t = threadIdx.x;
    int v = bsum[t];
    tmp[t] = v;
    __syncthreads();
    for (int off = 1; off < 256; off <<= 1) {
        int u = (t >= off) ? tmp[t - off] : 0;
        __syncthreads();
        tmp[t] += u;
        __syncthreads();
    }
    boff[t] = tmp[t] - v;
}
__global__ void k_scan3(int* __restrict__ rp, const int* __restrict__ boff) {
    int gid = blockIdx.x * 256 + threadIdx.x;
    rp[gid] += boff[gid >> 8];
    if (gid == 0) rp[NN] = FULLE;
}

// ---------------------------------------------------------------------------
// K4: self-loop slot (at rp[n]) + dinv. loop_attr = la/max(cnt,1).
__global__ void k_self(const int* __restrict__ cnt, const int* __restrict__ rp,
                       const float* __restrict__ la,
                       const float* __restrict__ a_src, const float* __restrict__ a_dst,
                       const float* __restrict__ acoef,
                       int* __restrict__ src_idx, float* __restrict__ alpha,
                       float* __restrict__ dinv) {
    int n = blockIdx.x * 256 + threadIdx.x;
    int c = cnt[n];
    int slot = rp[n];
    src_idx[slot] = n;
    float inv = 1.f / fmaxf((float)c, 1.f);
    float l0 = la[2 * n] * inv, l1 = la[2 * n + 1] * inv;
#pragma unroll
    for (int h = 0; h < 3; ++h) {
        float v = a_src[n * 3 + h] + a_dst[n * 3 + h] + l0 * acoef[h] + l1 * acoef[3 + h];
        v = v >= 0.f ? v : NEG * v;       // leaky_relu
        alpha[slot * 3 + h] = v;
    }
    dinv[n] = rsqrtf((float)c + 1.f);
}

// K5: fill real edges into CSR (slots rp[d]+1+pos), raw leaky-relu'd alpha
__global__ void k_edges(const int* __restrict__ ei, const float* __restrict__ ea,
                        const int* __restrict__ rp, int* __restrict__ fill,
                        const float* __restrict__ a_src, const float* __restrict__ a_dst,
                        const float* __restrict__ acoef,
                        int* __restrict__ src_idx, float* __restrict__ alpha) {
    int e = blockIdx.x * 256 + threadIdx.x;
    int s = ei[e], d = ei[EE + e];
    int pos = atomicAdd(&fill[d], 1);
    int slot = rp[d] + 1 + pos;
    src_idx[slot] = s;
    float e0 = ea[2 * e], e1 = ea[2 * e + 1];
#pragma unroll
    for (int h = 0; h < 3; ++h) {
        float v = a_src[s * 3 + h] + a_dst[d * 3 + h] + e0 * acoef[h] + e1 * acoef[3 + h];
        v = v >= 0.f ? v : NEG * v;
        alpha[slot * 3 + h] = v;
    }
}

// ---------------------------------------------------------------------------
// K6: softmax + weighted aggregation. Wave per node; lane = channel c,
// 3 heads per lane. x1 = relu(agg + b_gat); xw = x1 . W_gcn (wave-reduced).
__global__ __launch_bounds__(256) void k_agg(
    const int* __restrict__ rp, const int* __restrict__ src_idx,
    const float* __restrict__ alpha, const float* __restrict__ xp,
    const float* __restrict__ b_gat, const float* __restrict__ W_gcn,
    float* __restrict__ x1, float* __restrict__ xw) {
    int wave = threadIdx.x >> 6, lane = threadIdx.x & 63;
    int n = blockIdx.x * 4 + wave;
    int sb = rp[n], se = rp[n + 1];
    float m0 = -1e30f, m1 = -1e30f, m2 = -1e30f;
    for (int s = sb; s < se; ++s) {
        m0 = fmaxf(m0, alpha[s * 3]);
        m1 = fmaxf(m1, alpha[s * 3 + 1]);
        m2 = fmaxf(m2, alpha[s * 3 + 2]);
    }
    float d0 = 0.f, d1 = 0.f, d2 = 0.f, a0 = 0.f, a1 = 0.f, a2 = 0.f;
    for (int s = sb; s < se; ++s) {
        int src = src_idx[s];
        float w0 = expf(alpha[s * 3]     - m0);
        float w1 = expf(alpha[s * 3 + 1] - m1);
        float w2 = expf(alpha[s * 3 + 2] - m2);
        d0 += w0; d1 += w1; d2 += w2;
        const float* xr = &xp[(size_t)src * HCC];
        a0 += w0 * xr[lane];
        a1 += w1 * xr[64 + lane];
        a2 += w2 * xr[128 + lane];
    }
    float v0 = fmaxf(a0 / (d0 + 1e-16f) + b_gat[lane], 0.f);
    float v1 = fmaxf(a1 / (d1 + 1e-16f) + b_gat[64 + lane], 0.f);
    float v2 = fmaxf(a2 / (d2 + 1e-16f) + b_gat[128 + lane], 0.f);
    size_t nb = (size_t)n * HCC;
    x1[nb + lane] = v0; x1[nb + 64 + lane] = v1; x1[nb + 128 + lane] = v2;
    float p = v0 * W_gcn[lane] + v1 * W_gcn[64 + lane] + v2 * W_gcn[128 + lane];
    for (int off = 32; off > 0; off >>= 1) p += __shfl_down(p, off, 64);
    if (lane == 0) xw[n] = p;
}

// ---------------------------------------------------------------------------
// K7: GCN score. Self-loop slot (src=n) provides the dinv^2*xw term exactly.
__global__ void k_score(const int* __restrict__ rp, const int* __restrict__ src_idx,
                        const float* __restrict__ xw, const float* __restrict__ dinv,
                        const float* __restrict__ b_gcn, float* __restrict__ score) {
    int n = blockIdx.x * 256 + threadIdx.x;
    float acc = 0.f;
    int e0 = rp[n], e1 = rp[n + 1];
    for (int s = e0; s < e1; ++s) {
        int src = src_idx[s];
        acc += dinv[src] * xw[src];
    }
    score[n] = b_gcn[0] + dinv[n] * acc;
}

// ---------------------------------------------------------------------------
// K8: per-graph top-k (rank = stable double-argsort semantics) + readout
__global__ __launch_bounds__(512) void k_pool(
    const float* __restrict__ score, const float* __restrict__ x1,
    float* __restrict__ r) {
    __shared__ float s_l[512], ts[512];
    __shared__ int sel[512];
    int g = blockIdx.x, t = threadIdx.x;
    int base = g * NPGC;
    float si = score[base + t];
    s_l[t] = si;
    __syncthreads();
    int rank = 0;
    for (int j = 0; j < 512; ++j) {
        float sj = s_l[j];
        rank += (sj > si) || (sj == si && j < t);
    }
    sel[t] = (rank < KSEL) ? 1 : 0;
    ts[t] = tanhf(si);
    __syncthreads();
    if (t < HCC) {
        float mx = -1e30f, sm = 0.f;
        for (int i = 0; i < 512; ++i) {
            if (sel[i]) {
                float v = x1[(size_t)(base + i) * HCC + t] * ts[i];
                mx = fmaxf(mx, v);
                sm += v;
            }
        }
        r[g * 384 + t] = mx;
        r[g * 384 + 192 + t] = sm * (1.f / (float)KSEL);
    }
}

// ---------------------------------------------------------------------------
// K9: classifier MLP + log_softmax, one block per graph
__global__ __launch_bounds__(128) void k_mlp(
    const float* __restrict__ r,
    const float* __restrict__ W1, const float* __restrict__ b1,
    const float* __restrict__ W2, const float* __restrict__ b2,
    const float* __restrict__ W3, const float* __restrict__ b3,
    float* __restrict__ out) {
    __shared__ float rs[384], h1[64], h2[32], lg[10], mls;
    int g = blockIdx.x, t = threadIdx.x;
    for (int i = t; i < 384; i += 128) rs[i] = r[g * 384 + i];
    __syncthreads();
    if (t < 64) {
        float s = b1[t];
        for (int k = 0; k < 384; ++k) s += rs[k] * W1[t * 384 + k];
        h1[t] = fmaxf(s, 0.f);
    }
    __syncthreads();
    if (t < 32) {
        float s = b2[t];
        for (int k = 0; k < 64; ++k) s += h1[k] * W2[t * 64 + k];
        h2[t] = fmaxf(s, 0.f);
    }
    __syncthreads();
    if (t < 10) {
        float s = b3[t];
        for (int k = 0; k < 32; ++k) s += h2[k] * W3[t * 32 + k];
        lg[t] = s;
    }
    __syncthreads();
    if (t == 0) {
        float mx = lg[0];
        for (int j = 1; j < 10; ++j) mx = fmaxf(mx, lg[j]);
        float se = 0.f;
        for (int j = 0; j < 10; ++j) se += expf(lg[j] - mx);
        mls = mx + logf(se);
    }
    __syncthreads();
    if (t < 10) out[g * 10 + t] = lg[t] - mls;
}

// ---------------------------------------------------------------------------
extern "C" void kernel_launch(void* const* d_in, const int* in_sizes, int n_in,
                              void* d_out, int out_size, void* d_ws, size_t ws_size,
                              hipStream_t stream) {
    const float* x        = (const float*)d_in[0];
    const int*   ei       = (const int*)d_in[1];
    const float* ea       = (const float*)d_in[2];
    // d_in[3] = batch (unused: graphs are contiguous uniform blocks)
    const float* W_lin    = (const float*)d_in[4];
    const float* b_lin    = (const float*)d_in[5];
    const float* W_src    = (const float*)d_in[6];
    const float* att_src  = (const float*)d_in[7];
    const float* att_dst  = (const float*)d_in[8];
    const float* W_edge   = (const float*)d_in[9];
    const float* att_edge = (const float*)d_in[10];
    const float* b_gat    = (const float*)d_in[11];
    const float* W_gcn    = (const float*)d_in[12];
    const float* b_gcn    = (const float*)d_in[13];
    const float* W1 = (const float*)d_in[14]; const float* b1 = (const float*)d_in[15];
    const float* W2 = (const float*)d_in[16]; const float* b2 = (const float*)d_in[17];
    const float* W3 = (const float*)d_in[18]; const float* b3 = (const float*)d_in[19];
    float* out = (float*)d_out;

    char* ws = (char*)d_ws;
    size_t off = 0;
    auto alloc = [&](size_t bytes) {
        size_t r = off;
        off += (bytes + 255) & ~(size_t)255;
        return r;
    };
    float* xp      = (float*)(ws + alloc((size_t)NN * HCC * 4));   // 50.3 MB
    float* x1      = (float*)(ws + alloc((size_t)NN * HCC * 4));   // 50.3 MB
    float* a_src   = (float*)(ws + alloc((size_t)NN * 3 * 4));
    float* a_dst   = (float*)(ws + alloc((size_t)NN * 3 * 4));
    char*  zreg    = ws + alloc((size_t)NN * 16);   // cnt | fill | la (zeroed)
    int*   cnt     = (int*)zreg;
    int*   fill    = (int*)(zreg + (size_t)NN * 4);
    float* la      = (float*)(zreg + (size_t)NN * 8);
    int*   rp      = (int*)(ws + alloc((size_t)(NN + 1) * 4));
    int*   bsum    = (int*)(ws + alloc(256 * 4));
    int*   boff    = (int*)(ws + alloc(256 * 4));
    int*   src_idx = (int*)(ws + alloc((size_t)FULLE * 4));        // 2.4 MB
    float* alpha   = (float*)(ws + alloc((size_t)FULLE * 3 * 4));  // 7.1 MB
    float* xw      = (float*)(ws + alloc((size_t)NN * 4));
    float* dinv    = (float*)(ws + alloc((size_t)NN * 4));
    float* score   = (float*)(ws + alloc((size_t)NN * 4));
    float* acoef   = (float*)(ws + alloc(8 * 4));
    float* rbuf    = (float*)(ws + alloc((size_t)BB * 384 * 4));

    hipMemsetAsync(zreg, 0, (size_t)NN * 16, stream);
    k_acoef<<<1, 192, 0, stream>>>(W_edge, att_edge, acoef);
    k_feat<<<NN / 32, 128, 0, stream>>>(x, W_lin, b_lin, W_src, att_src, att_dst,
                                        xp, a_src, a_dst);
    k_deg<<<EE / 256, 256, 0, stream>>>(ei, ea, cnt, la);
    k_scan1<<<NN / 256, 256, 0, stream>>>(cnt, rp, bsum);
    k_scan2<<<1, 256, 0, stream>>>(bsum, boff);
    k_scan3<<<NN / 256, 256, 0, stream>>>(rp, boff);
    k_self<<<NN / 256, 256, 0, stream>>>(cnt, rp, la, a_src, a_dst, acoef,
                                         src_idx, alpha, dinv);
    k_edges<<<EE / 256, 256, 0, stream>>>(ei, ea, rp, fill, a_src, a_dst, acoef,
                                          src_idx, alpha);
    k_agg<<<NN / 4, 256, 0, stream>>>(rp, src_idx, alpha, xp, b_gat, W_gcn, x1, xw);
    k_score<<<NN / 256, 256, 0, stream>>>(rp, src_idx, xw, dinv, b_gcn, score);
    k_pool<<<BB, 512, 0, stream>>>(score, x1, rbuf);
    k_mlp<<<BB, 128, 0, stream>>>(rbuf, W1, b1, W2, b2, W3, b3, out);
}

// Round 2
// 440.086 us; speedup vs baseline: 1.4860x; 1.4860x over previous
//
#include <hip/hip_runtime.h>
#include <hip/hip_bf16.h>
#include <math.h>

#define NN   65536
#define EE   524288
#define BB   128
#define NPGC 512
#define HCC  192
#define KSEL 256
#define FULLE (EE + NN)   // 589824
#define NEG  0.2f

// ---------------------------------------------------------------------------
// K-1: prep — transpose W_lin -> WlT[k][j] (128x32), W_src -> WsT[k][j]
// (32x192), and compute acoef (block 7).
__global__ void k_prep(const float* __restrict__ W_lin,
                       const float* __restrict__ W_src,
                       const float* __restrict__ W_edge,
                       const float* __restrict__ att_edge,
                       float* __restrict__ WlT, float* __restrict__ WsT,
                       float* __restrict__ acoef) {
    int gid = blockIdx.x * 256 + threadIdx.x;
    for (int o = gid; o < 4096; o += 2048) {          // W_lin [32][128]
        int j = o >> 7, k = o & 127;
        WlT[k * 32 + j] = W_lin[o];
    }
    for (int o = gid; o < 6144; o += 2048) {          // W_src [192][32]
        int j = o >> 5, k = o & 31;
        WsT[k * 192 + j] = W_src[o];
    }
    if (blockIdx.x == 7) {
        __shared__ float red[6];
        int t = threadIdx.x;
        if (t < 6) red[t] = 0.f;
        __syncthreads();
        if (t < 192) {
            float ae = att_edge[t];
            int h = t >> 6;
            atomicAdd(&red[h],     W_edge[2 * t]     * ae);
            atomicAdd(&red[3 + h], W_edge[2 * t + 1] * ae);
        }
        __syncthreads();
        if (t < 6) acoef[t] = red[t];
    }
}

// ---------------------------------------------------------------------------
// K1: per-node features, thread = node, NO LDS. Weights via block-uniform
// (scalar) loads; x streamed float4 per-lane; all accumulators in registers.
//  h = elu(x @ W_lin^T + b_lin)            [N,32]  (registers only)
//  xp = h @ W_src^T                        [N,192]
//  a_src[n,h] / a_dst[n,h] fused reductions
__global__ __launch_bounds__(256) void k_feat(
    const float* __restrict__ x, const float* __restrict__ WlT,
    const float* __restrict__ b_lin, const float* __restrict__ WsT,
    const float* __restrict__ att_src, const float* __restrict__ att_dst,
    float* __restrict__ xp, float* __restrict__ a_src, float* __restrict__ a_dst) {
    int n = blockIdx.x * 256 + threadIdx.x;
    const float* xr = x + (size_t)n * 128;

    float hreg[32];
#pragma unroll
    for (int j = 0; j < 32; ++j) hreg[j] = b_lin[j];

#pragma unroll 4
    for (int k0 = 0; k0 < 128; k0 += 4) {
        float4 a = *(const float4*)(xr + k0);
        const float* w0 = WlT + k0 * 32;
#pragma unroll
        for (int j = 0; j < 32; ++j) {
            hreg[j] += a.x * w0[j] + a.y * w0[32 + j] +
                       a.z * w0[64 + j] + a.w * w0[96 + j];
        }
    }
#pragma unroll
    for (int j = 0; j < 32; ++j)
        hreg[j] = hreg[j] > 0.f ? hreg[j] : expm1f(hreg[j]);   // ELU

    for (int h = 0; h < 3; ++h) {                    // per head: 64 accums
        float acc[64];
#pragma unroll
        for (int c = 0; c < 64; ++c) acc[c] = 0.f;
#pragma unroll 4
        for (int k = 0; k < 32; ++k) {
            float hk = hreg[k];
            const float* wr = WsT + k * 192 + h * 64;
#pragma unroll
            for (int c = 0; c < 64; ++c) acc[c] += hk * wr[c];
        }
        float as = 0.f, ad = 0.f;
        const float* ats = att_src + h * 64;
        const float* atd = att_dst + h * 64;
#pragma unroll
        for (int c = 0; c < 64; ++c) {
            as += acc[c] * ats[c];
            ad += acc[c] * atd[c];
        }
        a_src[n * 3 + h] = as;
        a_dst[n * 3 + h] = ad;
        float4* dst = (float4*)(xp + (size_t)n * HCC + h * 64);
#pragma unroll
        for (int q = 0; q < 16; ++q)
            dst[q] = make_float4(acc[4 * q], acc[4 * q + 1],
                                 acc[4 * q + 2], acc[4 * q + 3]);
    }
}

// ---------------------------------------------------------------------------
// K2: in-degree + loop_attr sums (edge-parallel)
__global__ void k_deg(const int* __restrict__ ei, const float* __restrict__ ea,
                      int* __restrict__ cnt, float* __restrict__ la) {
    int e = blockIdx.x * 256 + threadIdx.x;
    int d = ei[EE + e];
    atomicAdd(&cnt[d], 1);
    atomicAdd(&la[2 * d],     ea[2 * e]);
    atomicAdd(&la[2 * d + 1], ea[2 * e + 1]);
}

// ---------------------------------------------------------------------------
// K3: exclusive scan of sizes[n]=cnt[n]+1 -> row_ptr (2-level, 256x256)
__global__ __launch_bounds__(256) void k_scan1(const int* __restrict__ cnt,
                                               int* __restrict__ rp,
                                               int* __restrict__ bsum) {
    __shared__ int tmp[256];
    int t = threadIdx.x, gid = blockIdx.x * 256 + t;
    int v = cnt[gid] + 1;
    tmp[t] = v;
    __syncthreads();
    for (int off = 1; off < 256; off <<= 1) {
        int u = (t >= off) ? tmp[t - off] : 0;
        __syncthreads();
        tmp[t] += u;
        __syncthreads();
    }
    rp[gid] = tmp[t] - v;
    if (t == 255) bsum[blockIdx.x] = tmp[255];
}
__global__ __launch_bounds__(256) void k_scan2(const int* __restrict__ bsum,
                                               int* __restrict__ boff) {
    __shared__ int tmp[256];
    int t = threadIdx.x;
    int v = bsum[t];
    tmp[t] = v;
    __syncthreads();
    for (int off = 1; off < 256; off <<= 1) {
        int u = (t >= off) ? tmp[t - off] : 0;
        __syncthreads();
        tmp[t] += u;
        __syncthreads();
    }
    boff[t] = tmp[t] - v;
}
__global__ void k_scan3(int* __restrict__ rp, const int* __restrict__ boff) {
    int gid = blockIdx.x * 256 + threadIdx.x;
    rp[gid] += boff[gid >> 8];
    if (gid == 0) rp[NN] = FULLE;
}

// ---------------------------------------------------------------------------
// K4: self-loop slot (at rp[n]) + dinv. loop_attr = la/max(cnt,1).
__global__ void k_self(const int* __restrict__ cnt, const int* __restrict__ rp,
                       const float* __restrict__ la,
                       const float* __restrict__ a_src, const float* __restrict__ a_dst,
                       const float* __restrict__ acoef,
                       int* __restrict__ src_idx, float* __restrict__ alpha,
                       float* __restrict__ dinv) {
    int n = blockIdx.x * 256 + threadIdx.x;
    int c = cnt[n];
    int slot = rp[n];
    src_idx[slot] = n;
    float inv = 1.f / fmaxf((float)c, 1.f);
    float l0 = la[2 * n] * inv, l1 = la[2 * n + 1] * inv;
#pragma unroll
    for (int h = 0; h < 3; ++h) {
        float v = a_src[n * 3 + h] + a_dst[n * 3 + h] + l0 * acoef[h] + l1 * acoef[3 + h];
        v = v >= 0.f ? v : NEG * v;
        alpha[slot * 3 + h] = v;
    }
    dinv[n] = rsqrtf((float)c + 1.f);
}

// K5: fill real edges into CSR (slots rp[d]+1+pos), raw leaky-relu'd alpha
__global__ void k_edges(const int* __restrict__ ei, const float* __restrict__ ea,
                        const int* __restrict__ rp, int* __restrict__ fill,
                        const float* __restrict__ a_src, const float* __restrict__ a_dst,
                        const float* __restrict__ acoef,
                        int* __restrict__ src_idx, float* __restrict__ alpha) {
    int e = blockIdx.x * 256 + threadIdx.x;
    int s = ei[e], d = ei[EE + e];
    int pos = atomicAdd(&fill[d], 1);
    int slot = rp[d] + 1 + pos;
    src_idx[slot] = s;
    float e0 = ea[2 * e], e1 = ea[2 * e + 1];
#pragma unroll
    for (int h = 0; h < 3; ++h) {
        float v = a_src[s * 3 + h] + a_dst[d * 3 + h] + e0 * acoef[h] + e1 * acoef[3 + h];
        v = v >= 0.f ? v : NEG * v;
        alpha[slot * 3 + h] = v;
    }
}

// ---------------------------------------------------------------------------
// K6: softmax + weighted aggregation. Wave per node; fast path assigns one
// CSR slot per lane (in-degree+1 <= 64 always holds for this data; uniform
// fallback otherwise). Butterfly shuffles for max/sum; per-slot weights
// broadcast from lane registers via __shfl. Gather of xp is lane-coalesced.
__global__ __launch_bounds__(256) void k_agg(
    const int* __restrict__ rp, const int* __restrict__ src_idx,
    const float* __restrict__ alpha, const float* __restrict__ xp,
    const float* __restrict__ b_gat, const float* __restrict__ W_gcn,
    float* __restrict__ x1, float* __restrict__ xw) {
    int wave = threadIdx.x >> 6, lane = threadIdx.x & 63;
    int n = blockIdx.x * 4 + wave;
    int sb = rp[n], se = rp[n + 1];
    int cnt = se - sb;
    float a0 = 0.f, a1 = 0.f, a2 = 0.f;
    float i0, i1, i2;

    if (cnt <= 64) {
        int slot = sb + lane;
        bool valid = slot < se;
        float al0 = valid ? alpha[slot * 3]     : -1e30f;
        float al1 = valid ? alpha[slot * 3 + 1] : -1e30f;
        float al2 = valid ? alpha[slot * 3 + 2] : -1e30f;
        int srcl  = valid ? src_idx[slot] : 0;
        float m0 = al0, m1 = al1, m2 = al2;
#pragma unroll
        for (int msk = 32; msk > 0; msk >>= 1) {
            m0 = fmaxf(m0, __shfl_xor(m0, msk, 64));
            m1 = fmaxf(m1, __shfl_xor(m1, msk, 64));
            m2 = fmaxf(m2, __shfl_xor(m2, msk, 64));
        }
        float e0 = valid ? expf(al0 - m0) : 0.f;
        float e1 = valid ? expf(al1 - m1) : 0.f;
        float e2 = valid ? expf(al2 - m2) : 0.f;
        float d0 = e0, d1 = e1, d2 = e2;
#pragma unroll
        for (int msk = 32; msk > 0; msk >>= 1) {
            d0 += __shfl_xor(d0, msk, 64);
            d1 += __shfl_xor(d1, msk, 64);
            d2 += __shfl_xor(d2, msk, 64);
        }
        i0 = 1.f / (d0 + 1e-16f);
        i1 = 1.f / (d1 + 1e-16f);
        i2 = 1.f / (d2 + 1e-16f);
        for (int s = 0; s < cnt; ++s) {
            int src = __shfl(srcl, s, 64);
            float w0 = __shfl(e0, s, 64);
            float w1 = __shfl(e1, s, 64);
            float w2 = __shfl(e2, s, 64);
            const float* xr = xp + (size_t)src * HCC;
            a0 += w0 * xr[lane];
            a1 += w1 * xr[64 + lane];
            a2 += w2 * xr[128 + lane];
        }
    } else {                                     // never expected; safety
        float m0 = -1e30f, m1 = -1e30f, m2 = -1e30f;
        for (int s = sb; s < se; ++s) {
            m0 = fmaxf(m0, alpha[s * 3]);
            m1 = fmaxf(m1, alpha[s * 3 + 1]);
            m2 = fmaxf(m2, alpha[s * 3 + 2]);
        }
        float d0 = 0.f, d1 = 0.f, d2 = 0.f;
        for (int s = sb; s < se; ++s) {
            int src = src_idx[s];
            float w0 = expf(alpha[s * 3]     - m0);
            float w1 = expf(alpha[s * 3 + 1] - m1);
            float w2 = expf(alpha[s * 3 + 2] - m2);
            d0 += w0; d1 += w1; d2 += w2;
            const float* xr = xp + (size_t)src * HCC;
            a0 += w0 * xr[lane];
            a1 += w1 * xr[64 + lane];
            a2 += w2 * xr[128 + lane];
        }
        i0 = 1.f / (d0 + 1e-16f);
        i1 = 1.f / (d1 + 1e-16f);
        i2 = 1.f / (d2 + 1e-16f);
    }

    float v0 = fmaxf(a0 * i0 + b_gat[lane], 0.f);
    float v1 = fmaxf(a1 * i1 + b_gat[64 + lane], 0.f);
    float v2 = fmaxf(a2 * i2 + b_gat[128 + lane], 0.f);
    size_t nb = (size_t)n * HCC;
    x1[nb + lane] = v0; x1[nb + 64 + lane] = v1; x1[nb + 128 + lane] = v2;
    float p = v0 * W_gcn[lane] + v1 * W_gcn[64 + lane] + v2 * W_gcn[128 + lane];
    for (int off = 32; off > 0; off >>= 1) p += __shfl_down(p, off, 64);
    if (lane == 0) xw[n] = p;
}

// ---------------------------------------------------------------------------
// K7: GCN score. Self-loop slot (src=n) provides the dinv^2*xw term exactly.
__global__ void k_score(const int* __restrict__ rp, const int* __restrict__ src_idx,
                        const float* __restrict__ xw, const float* __restrict__ dinv,
                        const float* __restrict__ b_gcn, float* __restrict__ score) {
    int n = blockIdx.x * 256 + threadIdx.x;
    float acc = 0.f;
    int e0 = rp[n], e1 = rp[n + 1];
    for (int s = e0; s < e1; ++s) {
        int src = src_idx[s];
        acc += dinv[src] * xw[src];
    }
    score[n] = b_gcn[0] + dinv[n] * acc;
}

// ---------------------------------------------------------------------------
// K8: per-graph top-k (rank = stable double-argsort semantics) + readout
__global__ __launch_bounds__(512) void k_pool(
    const float* __restrict__ score, const float* __restrict__ x1,
    float* __restrict__ r) {
    __shared__ float s_l[512], ts[512];
    __shared__ int sel[512];
    int g = blockIdx.x, t = threadIdx.x;
    int base = g * NPGC;
    float si = score[base + t];
    s_l[t] = si;
    __syncthreads();
    int rank = 0;
    for (int j = 0; j < 512; ++j) {
        float sj = s_l[j];
        rank += (sj > si) || (sj == si && j < t);
    }
    sel[t] = (rank < KSEL) ? 1 : 0;
    ts[t] = tanhf(si);
    __syncthreads();
    if (t < HCC) {
        float mx = -1e30f, sm = 0.f;
        for (int i = 0; i < 512; ++i) {
            if (sel[i]) {
                float v = x1[(size_t)(base + i) * HCC + t] * ts[i];
                mx = fmaxf(mx, v);
                sm += v;
            }
        }
        r[g * 384 + t] = mx;
        r[g * 384 + 192 + t] = sm * (1.f / (float)KSEL);
    }
}

// ---------------------------------------------------------------------------
// K9: classifier MLP + log_softmax, one block per graph
__global__ __launch_bounds__(128) void k_mlp(
    const float* __restrict__ r,
    const float* __restrict__ W1, const float* __restrict__ b1,
    const float* __restrict__ W2, const float* __restrict__ b2,
    const float* __restrict__ W3, const float* __restrict__ b3,
    float* __restrict__ out) {
    __shared__ float rs[384], h1[64], h2[32], lg[10], mls;
    int g = blockIdx.x, t = threadIdx.x;
    for (int i = t; i < 384; i += 128) rs[i] = r[g * 384 + i];
    __syncthreads();
    if (t < 64) {
        float s = b1[t];
        for (int k = 0; k < 384; ++k) s += rs[k] * W1[t * 384 + k];
        h1[t] = fmaxf(s, 0.f);
    }
    __syncthreads();
    if (t < 32) {
        float s = b2[t];
        for (int k = 0; k < 64; ++k) s += h1[k] * W2[t * 64 + k];
        h2[t] = fmaxf(s, 0.f);
    }
    __syncthreads();
    if (t < 10) {
        float s = b3[t];
        for (int k = 0; k < 32; ++k) s += h2[k] * W3[t * 32 + k];
        lg[t] = s;
    }
    __syncthreads();
    if (t == 0) {
        float mx = lg[0];
        for (int j = 1; j < 10; ++j) mx = fmaxf(mx, lg[j]);
        float se = 0.f;
        for (int j = 0; j < 10; ++j) se += expf(lg[j] - mx);
        mls = mx + logf(se);
    }
    __syncthreads();
    if (t < 10) out[g * 10 + t] = lg[t] - mls;
}

// ---------------------------------------------------------------------------
extern "C" void kernel_launch(void* const* d_in, const int* in_sizes, int n_in,
                              void* d_out, int out_size, void* d_ws, size_t ws_size,
                              hipStream_t stream) {
    const float* x        = (const float*)d_in[0];
    const int*   ei       = (const int*)d_in[1];
    const float* ea       = (const float*)d_in[2];
    const float* W_lin    = (const float*)d_in[4];
    const float* b_lin    = (const float*)d_in[5];
    const float* W_src    = (const float*)d_in[6];
    const float* att_src  = (const float*)d_in[7];
    const float* att_dst  = (const float*)d_in[8];
    const float* W_edge   = (const float*)d_in[9];
    const float* att_edge = (const float*)d_in[10];
    const float* b_gat    = (const float*)d_in[11];
    const float* W_gcn    = (const float*)d_in[12];
    const float* b_gcn    = (const float*)d_in[13];
    const float* W1 = (const float*)d_in[14]; const float* b1 = (const float*)d_in[15];
    const float* W2 = (const float*)d_in[16]; const float* b2 = (const float*)d_in[17];
    const float* W3 = (const float*)d_in[18]; const float* b3 = (const float*)d_in[19];
    float* out = (float*)d_out;

    char* ws = (char*)d_ws;
    size_t off = 0;
    auto alloc = [&](size_t bytes) {
        size_t r = off;
        off += (bytes + 255) & ~(size_t)255;
        return r;
    };
    float* xp      = (float*)(ws + alloc((size_t)NN * HCC * 4));   // 50.3 MB
    float* x1      = (float*)(ws + alloc((size_t)NN * HCC * 4));   // 50.3 MB
    float* a_src   = (float*)(ws + alloc((size_t)NN * 3 * 4));
    float* a_dst   = (float*)(ws + alloc((size_t)NN * 3 * 4));
    char*  zreg    = ws + alloc((size_t)NN * 16);   // cnt | fill | la (zeroed)
    int*   cnt     = (int*)zreg;
    int*   fill    = (int*)(zreg + (size_t)NN * 4);
    float* la      = (float*)(zreg + (size_t)NN * 8);
    int*   rp      = (int*)(ws + alloc((size_t)(NN + 1) * 4));
    int*   bsum    = (int*)(ws + alloc(256 * 4));
    int*   boff    = (int*)(ws + alloc(256 * 4));
    int*   src_idx = (int*)(ws + alloc((size_t)FULLE * 4));        // 2.4 MB
    float* alpha   = (float*)(ws + alloc((size_t)FULLE * 3 * 4));  // 7.1 MB
    float* xw      = (float*)(ws + alloc((size_t)NN * 4));
    float* dinv    = (float*)(ws + alloc((size_t)NN * 4));
    float* score   = (float*)(ws + alloc((size_t)NN * 4));
    float* acoef   = (float*)(ws + alloc(8 * 4));
    float* rbuf    = (float*)(ws + alloc((size_t)BB * 384 * 4));
    float* WlT     = (float*)(ws + alloc(4096 * 4));
    float* WsT     = (float*)(ws + alloc(6144 * 4));

    hipMemsetAsync(zreg, 0, (size_t)NN * 16, stream);
    k_prep<<<8, 256, 0, stream>>>(W_lin, W_src, W_edge, att_edge, WlT, WsT, acoef);
    k_feat<<<NN / 256, 256, 0, stream>>>(x, WlT, b_lin, WsT, att_src, att_dst,
                                         xp, a_src, a_dst);
    k_deg<<<EE / 256, 256, 0, stream>>>(ei, ea, cnt, la);
    k_scan1<<<NN / 256, 256, 0, stream>>>(cnt, rp, bsum);
    k_scan2<<<1, 256, 0, stream>>>(bsum, boff);
    k_scan3<<<NN / 256, 256, 0, stream>>>(rp, boff);
    k_self<<<NN / 256, 256, 0, stream>>>(cnt, rp, la, a_src, a_dst, acoef,
                                         src_idx, alpha, dinv);
    k_edges<<<EE / 256, 256, 0, stream>>>(ei, ea, rp, fill, a_src, a_dst, acoef,
                                          src_idx, alpha);
    k_agg<<<NN / 4, 256, 0, stream>>>(rp, src_idx, alpha, xp, b_gat, W_gcn, x1, xw);
    k_score<<<NN / 256, 256, 0, stream>>>(rp, src_idx, xw, dinv, b_gcn, score);
    k_pool<<<BB, 512, 0, stream>>>(score, x1, rbuf);
    k_mlp<<<BB, 128, 0, stream>>>(rbuf, W1, b1, W2, b2, W3, b3, out);
}

// Round 3
// 372.990 us; speedup vs baseline: 1.7533x; 1.1799x over previous
//
#include <hip/hip_runtime.h>
#include <hip/hip_bf16.h>
#include <math.h>

#define NN   65536
#define EE   524288
#define BB   128
#define NPGC 512
#define HCC  192
#define KSEL 256
#define FULLE (EE + NN)   // 589824
#define NEG  0.2f
#define PSEG 8            // node segments per graph in pooling
#define SEGN (NPGC / PSEG)

// ---------------------------------------------------------------------------
// K-1: prep — transpose W_lin -> WlT[k][j] (128x32), W_src -> WsT[k][j]
// (32x192), and compute acoef (block 7).
__global__ void k_prep(const float* __restrict__ W_lin,
                       const float* __restrict__ W_src,
                       const float* __restrict__ W_edge,
                       const float* __restrict__ att_edge,
                       float* __restrict__ WlT, float* __restrict__ WsT,
                       float* __restrict__ acoef) {
    int gid = blockIdx.x * 256 + threadIdx.x;
    for (int o = gid; o < 4096; o += 2048) {          // W_lin [32][128]
        int j = o >> 7, k = o & 127;
        WlT[k * 32 + j] = W_lin[o];
    }
    for (int o = gid; o < 6144; o += 2048) {          // W_src [192][32]
        int j = o >> 5, k = o & 31;
        WsT[k * 192 + j] = W_src[o];
    }
    if (blockIdx.x == 7) {
        __shared__ float red[6];
        int t = threadIdx.x;
        if (t < 6) red[t] = 0.f;
        __syncthreads();
        if (t < 192) {
            float ae = att_edge[t];
            int h = t >> 6;
            atomicAdd(&red[h],     W_edge[2 * t]     * ae);
            atomicAdd(&red[3 + h], W_edge[2 * t + 1] * ae);
        }
        __syncthreads();
        if (t < 6) acoef[t] = red[t];
    }
}

// ---------------------------------------------------------------------------
// K1: per-node features, thread = node, NO LDS. Weights via block-uniform
// (scalar) loads; x streamed float4 per-lane; all accumulators in registers.
__global__ __launch_bounds__(256) void k_feat(
    const float* __restrict__ x, const float* __restrict__ WlT,
    const float* __restrict__ b_lin, const float* __restrict__ WsT,
    const float* __restrict__ att_src, const float* __restrict__ att_dst,
    float* __restrict__ xp, float* __restrict__ a_src, float* __restrict__ a_dst) {
    int n = blockIdx.x * 256 + threadIdx.x;
    const float* xr = x + (size_t)n * 128;

    float hreg[32];
#pragma unroll
    for (int j = 0; j < 32; ++j) hreg[j] = b_lin[j];

#pragma unroll 4
    for (int k0 = 0; k0 < 128; k0 += 4) {
        float4 a = *(const float4*)(xr + k0);
        const float* w0 = WlT + k0 * 32;
#pragma unroll
        for (int j = 0; j < 32; ++j) {
            hreg[j] += a.x * w0[j] + a.y * w0[32 + j] +
                       a.z * w0[64 + j] + a.w * w0[96 + j];
        }
    }
#pragma unroll
    for (int j = 0; j < 32; ++j)
        hreg[j] = hreg[j] > 0.f ? hreg[j] : expm1f(hreg[j]);   // ELU

    for (int h = 0; h < 3; ++h) {                    // per head: 64 accums
        float acc[64];
#pragma unroll
        for (int c = 0; c < 64; ++c) acc[c] = 0.f;
#pragma unroll 4
        for (int k = 0; k < 32; ++k) {
            float hk = hreg[k];
            const float* wr = WsT + k * 192 + h * 64;
#pragma unroll
            for (int c = 0; c < 64; ++c) acc[c] += hk * wr[c];
        }
        float as = 0.f, ad = 0.f;
        const float* ats = att_src + h * 64;
        const float* atd = att_dst + h * 64;
#pragma unroll
        for (int c = 0; c < 64; ++c) {
            as += acc[c] * ats[c];
            ad += acc[c] * atd[c];
        }
        a_src[n * 3 + h] = as;
        a_dst[n * 3 + h] = ad;
        float4* dst = (float4*)(xp + (size_t)n * HCC + h * 64);
#pragma unroll
        for (int q = 0; q < 16; ++q)
            dst[q] = make_float4(acc[4 * q], acc[4 * q + 1],
                                 acc[4 * q + 2], acc[4 * q + 3]);
    }
}

// ---------------------------------------------------------------------------
// K2: in-degree + loop_attr sums (edge-parallel)
__global__ void k_deg(const int* __restrict__ ei, const float* __restrict__ ea,
                      int* __restrict__ cnt, float* __restrict__ la) {
    int e = blockIdx.x * 256 + threadIdx.x;
    int d = ei[EE + e];
    atomicAdd(&cnt[d], 1);
    atomicAdd(&la[2 * d],     ea[2 * e]);
    atomicAdd(&la[2 * d + 1], ea[2 * e + 1]);
}

// ---------------------------------------------------------------------------
// K3: exclusive scan of sizes[n]=cnt[n]+1 -> row_ptr (2-level, 256x256)
__global__ __launch_bounds__(256) void k_scan1(const int* __restrict__ cnt,
                                               int* __restrict__ rp,
                                               int* __restrict__ bsum) {
    __shared__ int tmp[256];
    int t = threadIdx.x, gid = blockIdx.x * 256 + t;
    int v = cnt[gid] + 1;
    tmp[t] = v;
    __syncthreads();
    for (int off = 1; off < 256; off <<= 1) {
        int u = (t >= off) ? tmp[t - off] : 0;
        __syncthreads();
        tmp[t] += u;
        __syncthreads();
    }
    rp[gid] = tmp[t] - v;
    if (t == 255) bsum[blockIdx.x] = tmp[255];
}
__global__ __launch_bounds__(256) void k_scan2(const int* __restrict__ bsum,
                                               int* __restrict__ boff) {
    __shared__ int tmp[256];
    int t = threadIdx.x;
    int v = bsum[t];
    tmp[t] = v;
    __syncthreads();
    for (int off = 1; off < 256; off <<= 1) {
        int u = (t >= off) ? tmp[t - off] : 0;
        __syncthreads();
        tmp[t] += u;
        __syncthreads();
    }
    boff[t] = tmp[t] - v;
}
__global__ void k_scan3(int* __restrict__ rp, const int* __restrict__ boff) {
    int gid = blockIdx.x * 256 + threadIdx.x;
    rp[gid] += boff[gid >> 8];
    if (gid == 0) rp[NN] = FULLE;
}

// ---------------------------------------------------------------------------
// K4: self-loop slot (at rp[n]) + dinv. loop_attr = la/max(cnt,1).
__global__ void k_self(const int* __restrict__ cnt, const int* __restrict__ rp,
                       const float* __restrict__ la,
                       const float* __restrict__ a_src, const float* __restrict__ a_dst,
                       const float* __restrict__ acoef,
                       int* __restrict__ src_idx, float* __restrict__ alpha,
                       float* __restrict__ dinv) {
    int n = blockIdx.x * 256 + threadIdx.x;
    int c = cnt[n];
    int slot = rp[n];
    src_idx[slot] = n;
    float inv = 1.f / fmaxf((float)c, 1.f);
    float l0 = la[2 * n] * inv, l1 = la[2 * n + 1] * inv;
#pragma unroll
    for (int h = 0; h < 3; ++h) {
        float v = a_src[n * 3 + h] + a_dst[n * 3 + h] + l0 * acoef[h] + l1 * acoef[3 + h];
        v = v >= 0.f ? v : NEG * v;
        alpha[slot * 3 + h] = v;
    }
    dinv[n] = rsqrtf((float)c + 1.f);
}

// K5: fill real edges into CSR (slots rp[d]+1+pos), raw leaky-relu'd alpha
__global__ void k_edges(const int* __restrict__ ei, const float* __restrict__ ea,
                        const int* __restrict__ rp, int* __restrict__ fill,
                        const float* __restrict__ a_src, const float* __restrict__ a_dst,
                        const float* __restrict__ acoef,
                        int* __restrict__ src_idx, float* __restrict__ alpha) {
    int e = blockIdx.x * 256 + threadIdx.x;
    int s = ei[e], d = ei[EE + e];
    int pos = atomicAdd(&fill[d], 1);
    int slot = rp[d] + 1 + pos;
    src_idx[slot] = s;
    float e0 = ea[2 * e], e1 = ea[2 * e + 1];
#pragma unroll
    for (int h = 0; h < 3; ++h) {
        float v = a_src[s * 3 + h] + a_dst[d * 3 + h] + e0 * acoef[h] + e1 * acoef[3 + h];
        v = v >= 0.f ? v : NEG * v;
        alpha[slot * 3 + h] = v;
    }
}

// ---------------------------------------------------------------------------
// K6: softmax + weighted aggregation. Wave per node; slot-per-lane fast path.
__global__ __launch_bounds__(256) void k_agg(
    const int* __restrict__ rp, const int* __restrict__ src_idx,
    const float* __restrict__ alpha, const float* __restrict__ xp,
    const float* __restrict__ b_gat, const float* __restrict__ W_gcn,
    float* __restrict__ x1, float* __restrict__ xw) {
    int wave = threadIdx.x >> 6, lane = threadIdx.x & 63;
    int n = blockIdx.x * 4 + wave;
    int sb = rp[n], se = rp[n + 1];
    int cnt = se - sb;
    float a0 = 0.f, a1 = 0.f, a2 = 0.f;
    float i0, i1, i2;

    if (cnt <= 64) {
        int slot = sb + lane;
        bool valid = slot < se;
        float al0 = valid ? alpha[slot * 3]     : -1e30f;
        float al1 = valid ? alpha[slot * 3 + 1] : -1e30f;
        float al2 = valid ? alpha[slot * 3 + 2] : -1e30f;
        int srcl  = valid ? src_idx[slot] : 0;
        float m0 = al0, m1 = al1, m2 = al2;
#pragma unroll
        for (int msk = 32; msk > 0; msk >>= 1) {
            m0 = fmaxf(m0, __shfl_xor(m0, msk, 64));
            m1 = fmaxf(m1, __shfl_xor(m1, msk, 64));
            m2 = fmaxf(m2, __shfl_xor(m2, msk, 64));
        }
        float e0 = valid ? expf(al0 - m0) : 0.f;
        float e1 = valid ? expf(al1 - m1) : 0.f;
        float e2 = valid ? expf(al2 - m2) : 0.f;
        float d0 = e0, d1 = e1, d2 = e2;
#pragma unroll
        for (int msk = 32; msk > 0; msk >>= 1) {
            d0 += __shfl_xor(d0, msk, 64);
            d1 += __shfl_xor(d1, msk, 64);
            d2 += __shfl_xor(d2, msk, 64);
        }
        i0 = 1.f / (d0 + 1e-16f);
        i1 = 1.f / (d1 + 1e-16f);
        i2 = 1.f / (d2 + 1e-16f);
        for (int s = 0; s < cnt; ++s) {
            int src = __shfl(srcl, s, 64);
            float w0 = __shfl(e0, s, 64);
            float w1 = __shfl(e1, s, 64);
            float w2 = __shfl(e2, s, 64);
            const float* xr = xp + (size_t)src * HCC;
            a0 += w0 * xr[lane];
            a1 += w1 * xr[64 + lane];
            a2 += w2 * xr[128 + lane];
        }
    } else {                                     // never expected; safety
        float m0 = -1e30f, m1 = -1e30f, m2 = -1e30f;
        for (int s = sb; s < se; ++s) {
            m0 = fmaxf(m0, alpha[s * 3]);
            m1 = fmaxf(m1, alpha[s * 3 + 1]);
            m2 = fmaxf(m2, alpha[s * 3 + 2]);
        }
        float d0 = 0.f, d1 = 0.f, d2 = 0.f;
        for (int s = sb; s < se; ++s) {
            int src = src_idx[s];
            float w0 = expf(alpha[s * 3]     - m0);
            float w1 = expf(alpha[s * 3 + 1] - m1);
            float w2 = expf(alpha[s * 3 + 2] - m2);
            d0 += w0; d1 += w1; d2 += w2;
            const float* xr = xp + (size_t)src * HCC;
            a0 += w0 * xr[lane];
            a1 += w1 * xr[64 + lane];
            a2 += w2 * xr[128 + lane];
        }
        i0 = 1.f / (d0 + 1e-16f);
        i1 = 1.f / (d1 + 1e-16f);
        i2 = 1.f / (d2 + 1e-16f);
    }

    float v0 = fmaxf(a0 * i0 + b_gat[lane], 0.f);
    float v1 = fmaxf(a1 * i1 + b_gat[64 + lane], 0.f);
    float v2 = fmaxf(a2 * i2 + b_gat[128 + lane], 0.f);
    size_t nb = (size_t)n * HCC;
    x1[nb + lane] = v0; x1[nb + 64 + lane] = v1; x1[nb + 128 + lane] = v2;
    float p = v0 * W_gcn[lane] + v1 * W_gcn[64 + lane] + v2 * W_gcn[128 + lane];
    for (int off = 32; off > 0; off >>= 1) p += __shfl_down(p, off, 64);
    if (lane == 0) xw[n] = p;
}

// ---------------------------------------------------------------------------
// K7: GCN score. Self-loop slot (src=n) provides the dinv^2*xw term exactly.
__global__ void k_score(const int* __restrict__ rp, const int* __restrict__ src_idx,
                        const float* __restrict__ xw, const float* __restrict__ dinv,
                        const float* __restrict__ b_gcn, float* __restrict__ score) {
    int n = blockIdx.x * 256 + threadIdx.x;
    float acc = 0.f;
    int e0 = rp[n], e1 = rp[n + 1];
    for (int s = e0; s < e1; ++s) {
        int src = src_idx[s];
        acc += dinv[src] * xw[src];
    }
    score[n] = b_gcn[0] + dinv[n] * acc;
}

// ---------------------------------------------------------------------------
// K8a: per-graph top-k rank (stable double-argsort semantics) -> sel, tanh(s)
__global__ __launch_bounds__(512) void k_rank(
    const float* __restrict__ score, int* __restrict__ sel,
    float* __restrict__ ts) {
    __shared__ float s_l[512];
    int g = blockIdx.x, t = threadIdx.x;
    int base = g * NPGC;
    float si = score[base + t];
    s_l[t] = si;
    __syncthreads();
    int rank = 0;
    for (int j = 0; j < 512; ++j) {
        float sj = s_l[j];
        rank += (sj > si) || (sj == si && j < t);
    }
    sel[base + t] = (rank < KSEL) ? 1 : 0;
    ts[base + t] = tanhf(si);
}

// K8b: partial masked max/sum over a 64-node segment; block = (graph, seg),
// 192 threads = channel. Coalesced 768B row reads, 3072 waves total.
__global__ __launch_bounds__(192) void k_pool2(
    const int* __restrict__ sel, const float* __restrict__ ts,
    const float* __restrict__ x1,
    float* __restrict__ pmax, float* __restrict__ psum) {
    __shared__ float ts_s[SEGN];
    __shared__ int sel_s[SEGN];
    int g = blockIdx.x >> 3, seg = blockIdx.x & 7, t = threadIdx.x;
    int nb = g * NPGC + seg * SEGN;
    if (t < SEGN) {
        ts_s[t] = ts[nb + t];
        sel_s[t] = sel[nb + t];
    }
    __syncthreads();
    float mx = -1e30f, sm = 0.f;
    for (int i = 0; i < SEGN; ++i) {
        if (sel_s[i]) {
            float v = x1[(size_t)(nb + i) * HCC + t] * ts_s[i];
            mx = fmaxf(mx, v);
            sm += v;
        }
    }
    pmax[(size_t)blockIdx.x * HCC + t] = mx;
    psum[(size_t)blockIdx.x * HCC + t] = sm;
}

// K8c: combine 8 partials -> r[g*384 + {t, 192+t}]
__global__ __launch_bounds__(192) void k_pool3(
    const float* __restrict__ pmax, const float* __restrict__ psum,
    float* __restrict__ r) {
    int g = blockIdx.x, t = threadIdx.x;
    float mx = -1e30f, sm = 0.f;
#pragma unroll
    for (int s = 0; s < PSEG; ++s) {
        mx = fmaxf(mx, pmax[(size_t)(g * PSEG + s) * HCC + t]);
        sm += psum[(size_t)(g * PSEG + s) * HCC + t];
    }
    r[g * 384 + t] = mx;
    r[g * 384 + 192 + t] = sm * (1.f / (float)KSEL);
}

// ---------------------------------------------------------------------------
// K9: classifier MLP + log_softmax, one block per graph
__global__ __launch_bounds__(128) void k_mlp(
    const float* __restrict__ r,
    const float* __restrict__ W1, const float* __restrict__ b1,
    const float* __restrict__ W2, const float* __restrict__ b2,
    const float* __restrict__ W3, const float* __restrict__ b3,
    float* __restrict__ out) {
    __shared__ float rs[384], h1[64], h2[32], lg[10], mls;
    int g = blockIdx.x, t = threadIdx.x;
    for (int i = t; i < 384; i += 128) rs[i] = r[g * 384 + i];
    __syncthreads();
    if (t < 64) {
        float s = b1[t];
        for (int k = 0; k < 384; ++k) s += rs[k] * W1[t * 384 + k];
        h1[t] = fmaxf(s, 0.f);
    }
    __syncthreads();
    if (t < 32) {
        float s = b2[t];
        for (int k = 0; k < 64; ++k) s += h1[k] * W2[t * 64 + k];
        h2[t] = fmaxf(s, 0.f);
    }
    __syncthreads();
    if (t < 10) {
        float s = b3[t];
        for (int k = 0; k < 32; ++k) s += h2[k] * W3[t * 32 + k];
        lg[t] = s;
    }
    __syncthreads();
    if (t == 0) {
        float mx = lg[0];
        for (int j = 1; j < 10; ++j) mx = fmaxf(mx, lg[j]);
        float se = 0.f;
        for (int j = 0; j < 10; ++j) se += expf(lg[j] - mx);
        mls = mx + logf(se);
    }
    __syncthreads();
    if (t < 10) out[g * 10 + t] = lg[t] - mls;
}

// ---------------------------------------------------------------------------
extern "C" void kernel_launch(void* const* d_in, const int* in_sizes, int n_in,
                              void* d_out, int out_size, void* d_ws, size_t ws_size,
                              hipStream_t stream) {
    const float* x        = (const float*)d_in[0];
    const int*   ei       = (const int*)d_in[1];
    const float* ea       = (const float*)d_in[2];
    const float* W_lin    = (const float*)d_in[4];
    const float* b_lin    = (const float*)d_in[5];
    const float* W_src    = (const float*)d_in[6];
    const float* att_src  = (const float*)d_in[7];
    const float* att_dst  = (const float*)d_in[8];
    const float* W_edge   = (const float*)d_in[9];
    const float* att_edge = (const float*)d_in[10];
    const float* b_gat    = (const float*)d_in[11];
    const float* W_gcn    = (const float*)d_in[12];
    const float* b_gcn    = (const float*)d_in[13];
    const float* W1 = (const float*)d_in[14]; const float* b1 = (const float*)d_in[15];
    const float* W2 = (const float*)d_in[16]; const float* b2 = (const float*)d_in[17];
    const float* W3 = (const float*)d_in[18]; const float* b3 = (const float*)d_in[19];
    float* out = (float*)d_out;

    char* ws = (char*)d_ws;
    size_t off = 0;
    auto alloc = [&](size_t bytes) {
        size_t r = off;
        off += (bytes + 255) & ~(size_t)255;
        return r;
    };
    float* xp      = (float*)(ws + alloc((size_t)NN * HCC * 4));   // 50.3 MB
    float* x1      = (float*)(ws + alloc((size_t)NN * HCC * 4));   // 50.3 MB
    float* a_src   = (float*)(ws + alloc((size_t)NN * 3 * 4));
    float* a_dst   = (float*)(ws + alloc((size_t)NN * 3 * 4));
    char*  zreg    = ws + alloc((size_t)NN * 16);   // cnt | fill | la (zeroed)
    int*   cnt     = (int*)zreg;
    int*   fill    = (int*)(zreg + (size_t)NN * 4);
    float* la      = (float*)(zreg + (size_t)NN * 8);
    int*   rp      = (int*)(ws + alloc((size_t)(NN + 1) * 4));
    int*   bsum    = (int*)(ws + alloc(256 * 4));
    int*   boff    = (int*)(ws + alloc(256 * 4));
    int*   src_idx = (int*)(ws + alloc((size_t)FULLE * 4));        // 2.4 MB
    float* alpha   = (float*)(ws + alloc((size_t)FULLE * 3 * 4));  // 7.1 MB
    float* xw      = (float*)(ws + alloc((size_t)NN * 4));
    float* dinv    = (float*)(ws + alloc((size_t)NN * 4));
    float* score   = (float*)(ws + alloc((size_t)NN * 4));
    float* acoef   = (float*)(ws + alloc(8 * 4));
    float* rbuf    = (float*)(ws + alloc((size_t)BB * 384 * 4));
    float* WlT     = (float*)(ws + alloc(4096 * 4));
    float* WsT     = (float*)(ws + alloc(6144 * 4));
    int*   sel     = (int*)(ws + alloc((size_t)NN * 4));
    float* ts      = (float*)(ws + alloc((size_t)NN * 4));
    float* pmax    = (float*)(ws + alloc((size_t)BB * PSEG * HCC * 4));
    float* psum    = (float*)(ws + alloc((size_t)BB * PSEG * HCC * 4));

    hipMemsetAsync(zreg, 0, (size_t)NN * 16, stream);
    k_prep<<<8, 256, 0, stream>>>(W_lin, W_src, W_edge, att_edge, WlT, WsT, acoef);
    k_feat<<<NN / 256, 256, 0, stream>>>(x, WlT, b_lin, WsT, att_src, att_dst,
                                         xp, a_src, a_dst);
    k_deg<<<EE / 256, 256, 0, stream>>>(ei, ea, cnt, la);
    k_scan1<<<NN / 256, 256, 0, stream>>>(cnt, rp, bsum);
    k_scan2<<<1, 256, 0, stream>>>(bsum, boff);
    k_scan3<<<NN / 256, 256, 0, stream>>>(rp, boff);
    k_self<<<NN / 256, 256, 0, stream>>>(cnt, rp, la, a_src, a_dst, acoef,
                                         src_idx, alpha, dinv);
    k_edges<<<EE / 256, 256, 0, stream>>>(ei, ea, rp, fill, a_src, a_dst, acoef,
                                          src_idx, alpha);
    k_agg<<<NN / 4, 256, 0, stream>>>(rp, src_idx, alpha, xp, b_gat, W_gcn, x1, xw);
    k_score<<<NN / 256, 256, 0, stream>>>(rp, src_idx, xw, dinv, b_gcn, score);
    k_rank<<<BB, 512, 0, stream>>>(score, sel, ts);
    k_pool2<<<BB * PSEG, 192, 0, stream>>>(sel, ts, x1, pmax, psum);
    k_pool3<<<BB, 192, 0, stream>>>(pmax, psum, rbuf);
    k_mlp<<<BB, 128, 0, stream>>>(rbuf, W1, b1, W2, b2, W3, b3, out);
}